// Round 1
// baseline (7318.271 us; speedup 1.0000x reference)
//
#include <hip/hip_runtime.h>
#include <math.h>

#define LPAD  10240
#define NSEQ  10001
#define PADT  239
#define NPIX  10000

// ---------------------------------------------------------------------------
// Generic fp32 tiled GEMM: C = alpha*A@B (+diag) (+bias) (+resid) (*rowscale)
// 64x64 tile, 256 threads, 4x4 per-thread register tile. Supports:
//   - batch (grid.z strides), split-K with atomicAdd accumulate
//   - B transposed (B stored N x K row-major)
//   - qscale: multiply cols < 512 by 0.125 (q scaling inside qkv projection)
// ---------------------------------------------------------------------------
__global__ __launch_bounds__(256) void gemm_big(
    const float* __restrict__ A, int lda, long sA,
    const float* __restrict__ B, int ldb, long sB,
    float* __restrict__ C, int ldc, long sC,
    int M, int N, int K,
    float alpha, float diagc,
    const float* __restrict__ bias,
    const float* __restrict__ resid, int ldr,
    const float* __restrict__ rowscale, int rs_stride,
    int relu, int qscale, int btrans, int ksplit, int atomic)
{
    __shared__ float As[16][68];
    __shared__ float Bs[16][64];

    int bz = blockIdx.z / ksplit;
    int ks = blockIdx.z % ksplit;
    A += (size_t)bz * sA;
    B += (size_t)bz * sB;
    C += (size_t)bz * sC;

    int kchunk = (K + ksplit - 1) / ksplit;
    kchunk = (kchunk + 15) & ~15;
    int kbeg = ks * kchunk;
    int kend = kbeg + kchunk; if (kend > K) kend = K;

    int tid = threadIdx.x;
    int tx = tid & 15, ty = tid >> 4;
    int m0 = blockIdx.y * 64, n0 = blockIdx.x * 64;

    float acc[4][4];
    #pragma unroll
    for (int i = 0; i < 4; i++)
        #pragma unroll
        for (int j = 0; j < 4; j++) acc[i][j] = 0.f;

    for (int k0 = kbeg; k0 < kend; k0 += 16) {
        // A tile: 64 rows x 16 k
        {
            int r = tid >> 2;
            int kk = (tid & 3) * 4;
            int m = m0 + r;
            float4 av = make_float4(0.f, 0.f, 0.f, 0.f);
            if (m < M) av = *(const float4*)(A + (size_t)m * lda + k0 + kk);
            As[kk + 0][r] = av.x; As[kk + 1][r] = av.y;
            As[kk + 2][r] = av.z; As[kk + 3][r] = av.w;
        }
        // B tile: 16 k x 64 n
        if (!btrans) {
            int r = tid >> 6;      // 0..3
            int c = tid & 63;
            #pragma unroll
            for (int i = 0; i < 4; i++) {
                int kk = r + i * 4;
                Bs[kk][c] = B[(size_t)(k0 + kk) * ldb + n0 + c];
            }
        } else {
            int c = tid >> 2;      // 0..63
            int kk = (tid & 3) * 4;
            float4 bv = *(const float4*)(B + (size_t)(n0 + c) * ldb + k0 + kk);
            Bs[kk + 0][c] = bv.x; Bs[kk + 1][c] = bv.y;
            Bs[kk + 2][c] = bv.z; Bs[kk + 3][c] = bv.w;
        }
        __syncthreads();
        #pragma unroll
        for (int k = 0; k < 16; k++) {
            float4 a4 = *(const float4*)&As[k][ty * 4];
            float4 b4 = *(const float4*)&Bs[k][tx * 4];
            float a[4] = {a4.x, a4.y, a4.z, a4.w};
            float b[4] = {b4.x, b4.y, b4.z, b4.w};
            #pragma unroll
            for (int i = 0; i < 4; i++)
                #pragma unroll
                for (int j = 0; j < 4; j++) acc[i][j] += a[i] * b[j];
        }
        __syncthreads();
    }

    #pragma unroll
    for (int i = 0; i < 4; i++) {
        int m = m0 + ty * 4 + i;
        if (m >= M) continue;
        float rsc = rowscale ? rowscale[(size_t)bz * rs_stride + m] : 1.f;
        #pragma unroll
        for (int j = 0; j < 4; j++) {
            int n = n0 + tx * 4 + j;
            float v = alpha * acc[i][j];
            if (diagc != 0.f && m == n) v += diagc;
            if (qscale && n < 512) v *= 0.125f;
            if (bias) v += bias[n];
            if (resid) v += resid[(size_t)m * ldr + n];
            v *= rsc;
            if (relu) v = fmaxf(v, 0.f);
            float* cp = C + (size_t)m * ldc + n;
            if (atomic) atomicAdd(cp, v); else *cp = v;
        }
    }
}

// ---------------------------------------------------------------------------
// LayerNorm rows of 512: out = (x-mu)*rsqrt(var+1e-5)*g + b. 4 rows / block.
// ---------------------------------------------------------------------------
__global__ __launch_bounds__(256) void ln_kernel(
    const float* __restrict__ X, float* __restrict__ OUT,
    const float* __restrict__ g, const float* __restrict__ b, int nrows)
{
    int row = blockIdx.x * 4 + (threadIdx.x >> 6);
    int lane = threadIdx.x & 63;
    if (row >= nrows) return;
    const float* xr = X + (size_t)row * 512;
    float v[8]; float s = 0.f, s2 = 0.f;
    #pragma unroll
    for (int i = 0; i < 8; i++) { float t = xr[lane + i * 64]; v[i] = t; s += t; s2 += t * t; }
    for (int o = 1; o < 64; o <<= 1) { s += __shfl_xor(s, o, 64); s2 += __shfl_xor(s2, o, 64); }
    float mu = s * (1.f / 512.f);
    float var = s2 * (1.f / 512.f) - mu * mu;
    float rs = rsqrtf(var + 1e-5f);
    float* orow = OUT + (size_t)row * 512;
    #pragma unroll
    for (int i = 0; i < 8; i++) {
        int j = lane + i * 64;
        orow[j] = (v[i] - mu) * rs * g[j] + b[j];
    }
}

// ---------------------------------------------------------------------------
// Landmark means: ql[h][m][d] = mean_{li<40} q[m*40+li][h*64+d]; same for kl.
// ---------------------------------------------------------------------------
__global__ __launch_bounds__(64) void landmarks_kernel(
    const float* __restrict__ QKV, float* __restrict__ QL, float* __restrict__ KL)
{
    int mm = blockIdx.x, hh = blockIdx.y;
    int d = threadIdx.x;
    const float* base = QKV + (size_t)(mm * 40) * 1536 + hh * 64 + d;
    float sq = 0.f, sk = 0.f;
    for (int li = 0; li < 40; li++) {
        sq += base[(size_t)li * 1536];
        sk += base[(size_t)li * 1536 + 512];
    }
    QL[((size_t)hh * 256 + mm) * 64 + d] = sq * (1.f / 40.f);
    KL[((size_t)hh * 256 + mm) * 64 + d] = sk * (1.f / 40.f);
}

// ---------------------------------------------------------------------------
// Row softmax over ncols. norm=1: normalize in place. Always writes 1/sum.
// ---------------------------------------------------------------------------
__global__ __launch_bounds__(256) void row_softmax(
    float* __restrict__ S, float* __restrict__ LSUM, int ncols, int norm)
{
    int row = blockIdx.x;
    float* p = S + (size_t)row * ncols;
    int tid = threadIdx.x;
    __shared__ float sr1[4], sr2[4];
    float mx = -1e30f;
    for (int i = tid; i < ncols; i += 256) mx = fmaxf(mx, p[i]);
    for (int o = 1; o < 64; o <<= 1) mx = fmaxf(mx, __shfl_xor(mx, o, 64));
    if ((tid & 63) == 0) sr1[tid >> 6] = mx;
    __syncthreads();
    mx = fmaxf(fmaxf(sr1[0], sr1[1]), fmaxf(sr1[2], sr1[3]));
    float s = 0.f;
    for (int i = tid; i < ncols; i += 256) { float e = __expf(p[i] - mx); p[i] = e; s += e; }
    for (int o = 1; o < 64; o <<= 1) s += __shfl_xor(s, o, 64);
    if ((tid & 63) == 0) sr2[tid >> 6] = s;
    __syncthreads();
    s = sr2[0] + sr2[1] + sr2[2] + sr2[3];
    float inv = 1.f / s;
    if (tid == 0) LSUM[row] = inv;
    if (norm) for (int i = tid; i < ncols; i += 256) p[i] *= inv;
}

// ---------------------------------------------------------------------------
// Global pinv denom: scal[0]=max row |sum|, scal[1]=max col |sum| (across heads)
// ---------------------------------------------------------------------------
__global__ __launch_bounds__(256) void a2norms_kernel(
    const float* __restrict__ A2, float* __restrict__ scal)
{
    int hh = blockIdx.x, tid = threadIdx.x;
    const float* A = A2 + (size_t)hh * 65536;
    float rs = 0.f, cs = 0.f;
    for (int j = 0; j < 256; j++) {
        rs += fabsf(A[(size_t)tid * 256 + j]);
        cs += fabsf(A[(size_t)j * 256 + tid]);
    }
    __shared__ float sm[8];
    for (int o = 1; o < 64; o <<= 1) {
        rs = fmaxf(rs, __shfl_xor(rs, o, 64));
        cs = fmaxf(cs, __shfl_xor(cs, o, 64));
    }
    if ((tid & 63) == 0) { sm[tid >> 6] = rs; sm[4 + (tid >> 6)] = cs; }
    __syncthreads();
    if (tid == 0) {
        float rm = fmaxf(fmaxf(sm[0], sm[1]), fmaxf(sm[2], sm[3]));
        float cm = fmaxf(fmaxf(sm[4], sm[5]), fmaxf(sm[6], sm[7]));
        atomicMax((unsigned int*)&scal[0], __float_as_uint(rm));
        atomicMax((unsigned int*)&scal[1], __float_as_uint(cm));
    }
}

// z0 = a2^T / (rowmax*colmax)
__global__ __launch_bounds__(256) void z0_kernel(
    const float* __restrict__ A2, const float* __restrict__ scal, float* __restrict__ Z)
{
    int i = blockIdx.x, hh = blockIdx.y, j = threadIdx.x;
    float inv = 1.f / (scal[0] * scal[1]);
    Z[((size_t)hh * 256 + i) * 256 + j] = A2[((size_t)hh * 256 + j) * 256 + i] * inv;
}

// W1 = 7I - XZ
__global__ __launch_bounds__(256) void ew7_kernel(
    const float* __restrict__ XZ, float* __restrict__ W1)
{
    size_t idx = (size_t)blockIdx.x * 256 + threadIdx.x;
    if (idx >= (size_t)8 * 65536) return;
    int within = (int)(idx & 65535);
    int i = within >> 8, j = within & 255;
    W1[idx] = ((i == j) ? 7.f : 0.f) - XZ[idx];
}

// ---------------------------------------------------------------------------
// Fused a1 @ Z + depthwise token conv, in-place over q slice of QKV.
// Block: 32 tokens x 1 head. Thread (li=tid>>3, g=tid&7).
// ---------------------------------------------------------------------------
__global__ __launch_bounds__(256) void a1z_conv(
    float* __restrict__ QKV,
    const float* __restrict__ KLg,
    const float* __restrict__ ZMg,
    const float* __restrict__ resw,
    int T0)
{
    int hh = blockIdx.y;
    int t0 = T0 + blockIdx.x * 32;
    int tid = threadIdx.x;
    int li = tid >> 3, g = tid & 7;
    int tok = t0 + li;
    bool valid = tok < LPAD;

    __shared__ float qs[32][68];
    __shared__ float kz[64][68];
    __shared__ float sb[32][260];

    {
        const float* qp = QKV + (size_t)(valid ? tok : 0) * 1536 + hh * 64 + g * 8;
        float4 v0 = make_float4(0.f, 0.f, 0.f, 0.f), v1 = v0;
        if (valid) { v0 = *(const float4*)qp; v1 = *(const float4*)(qp + 4); }
        *(float4*)&qs[li][g * 8] = v0;
        *(float4*)&qs[li][g * 8 + 4] = v1;
    }
    // scores: 256 landmark cols in 4 chunks of 64
    for (int c = 0; c < 4; c++) {
        __syncthreads();
        {
            int j = tid >> 2, cc = (tid & 3) * 16;
            const float* kp = KLg + ((size_t)hh * 256 + c * 64 + j) * 64 + cc;
            #pragma unroll
            for (int i = 0; i < 16; i += 4)
                *(float4*)&kz[j][cc + i] = *(const float4*)(kp + i);
        }
        __syncthreads();
        #pragma unroll
        for (int jj = 0; jj < 8; jj++) {
            int j = g + jj * 8;           // stride-8 mapping: conflict-free banks
            float d = 0.f;
            #pragma unroll
            for (int k = 0; k < 64; k += 4) {
                float4 a = *(const float4*)&qs[li][k];
                float4 b = *(const float4*)&kz[j][k];
                d += a.x * b.x + a.y * b.y + a.z * b.z + a.w * b.w;
            }
            sb[li][c * 64 + j] = d;
        }
    }
    __syncthreads();
    // softmax over row (256)
    float mx = -1e30f;
    for (int t = 0; t < 32; t++) mx = fmaxf(mx, sb[li][g * 32 + t]);
    for (int o = 1; o < 8; o <<= 1) mx = fmaxf(mx, __shfl_xor(mx, o, 64));
    float ls = 0.f;
    for (int t = 0; t < 32; t++) {
        float e = __expf(sb[li][g * 32 + t] - mx);
        sb[li][g * 32 + t] = e; ls += e;
    }
    for (int o = 1; o < 8; o <<= 1) ls += __shfl_xor(ls, o, 64);
    float invl = 1.f / ls;
    // matvec with Z (256 x 64)
    float acc[8] = {0.f, 0.f, 0.f, 0.f, 0.f, 0.f, 0.f, 0.f};
    for (int c = 0; c < 4; c++) {
        __syncthreads();
        {
            int j = tid >> 2, cc = (tid & 3) * 16;
            const float* zp = ZMg + ((size_t)hh * 256 + c * 64 + j) * 64 + cc;
            #pragma unroll
            for (int i = 0; i < 16; i += 4)
                *(float4*)&kz[j][cc + i] = *(const float4*)(zp + i);
        }
        __syncthreads();
        for (int j = 0; j < 64; j++) {
            float p = sb[li][c * 64 + j];
            float4 z0 = *(const float4*)&kz[j][g * 8];
            float4 z1 = *(const float4*)&kz[j][g * 8 + 4];
            acc[0] += p * z0.x; acc[1] += p * z0.y; acc[2] += p * z0.z; acc[3] += p * z0.w;
            acc[4] += p * z1.x; acc[5] += p * z1.y; acc[6] += p * z1.z; acc[7] += p * z1.w;
        }
    }
    if (valid) {
        float cv[8] = {0.f, 0.f, 0.f, 0.f, 0.f, 0.f, 0.f, 0.f};
        const float* vbase = QKV + 1024 + hh * 64 + g * 8;
        for (int r = 0; r < 33; r++) {
            int ts = tok - 16 + r;
            if (ts < 0 || ts >= LPAD) continue;
            float wr = resw[hh * 33 + r];
            float4 v0 = *(const float4*)(vbase + (size_t)ts * 1536);
            float4 v1 = *(const float4*)(vbase + (size_t)ts * 1536 + 4);
            cv[0] += wr * v0.x; cv[1] += wr * v0.y; cv[2] += wr * v0.z; cv[3] += wr * v0.w;
            cv[4] += wr * v1.x; cv[5] += wr * v1.y; cv[6] += wr * v1.z; cv[7] += wr * v1.w;
        }
        float* op = QKV + (size_t)tok * 1536 + hh * 64 + g * 8;
        *(float4*)op = make_float4(acc[0] * invl + cv[0], acc[1] * invl + cv[1],
                                   acc[2] * invl + cv[2], acc[3] * invl + cv[3]);
        *(float4*)(op + 4) = make_float4(acc[4] * invl + cv[4], acc[5] * invl + cv[5],
                                         acc[6] * invl + cv[6], acc[7] * invl + cv[7]);
    }
}

// ---------------------------------------------------------------------------
// PPEG: y = (dw7+b7) + f + (dw5+b5) + (dw3+b3), 100x100, 512 ch, zero pad.
// Weights pre-transposed to [tap][512].
// ---------------------------------------------------------------------------
__global__ __launch_bounds__(256) void ppeg_kernel(
    const float* __restrict__ S, float* __restrict__ O,
    const float* __restrict__ w7t, const float* __restrict__ b7,
    const float* __restrict__ w5t, const float* __restrict__ b5,
    const float* __restrict__ w3t, const float* __restrict__ b3)
{
    int pos = blockIdx.x;
    int y = pos / 100, x = pos - y * 100;
    int c = blockIdx.y * 256 + threadIdx.x;
    float acc = S[(size_t)(1 + pos) * 512 + c] + b7[c] + b5[c] + b3[c];
    for (int dy = -3; dy <= 3; dy++) {
        int yy = y + dy; if ((unsigned)yy >= 100u) continue;
        for (int dx = -3; dx <= 3; dx++) {
            int xx = x + dx; if ((unsigned)xx >= 100u) continue;
            float v = S[(size_t)(1 + yy * 100 + xx) * 512 + c];
            float wsum = w7t[((dy + 3) * 7 + (dx + 3)) * 512 + c];
            if (dy >= -2 && dy <= 2 && dx >= -2 && dx <= 2)
                wsum += w5t[((dy + 2) * 5 + (dx + 2)) * 512 + c];
            if (dy >= -1 && dy <= 1 && dx >= -1 && dx <= 1)
                wsum += w3t[((dy + 1) * 3 + (dx + 1)) * 512 + c];
            acc += v * wsum;
        }
    }
    O[(size_t)(1 + pos) * 512 + c] = acc;
}

__global__ void transpose_w(const float* __restrict__ w, float* __restrict__ wt, int KK)
{
    int idx = blockIdx.x * 256 + threadIdx.x;
    if (idx >= 512 * KK) return;
    int c = idx / KK, k = idx - c * KK;
    wt[k * 512 + c] = w[idx];
}

// Final: LN(token0) @ fc2_w + fc2_b
__global__ __launch_bounds__(64) void final_kernel(
    const float* __restrict__ S, const float* __restrict__ g, const float* __restrict__ b,
    const float* __restrict__ w, const float* __restrict__ bb, float* __restrict__ out)
{
    int lane = threadIdx.x;
    float v[8]; float s = 0.f, s2 = 0.f;
    #pragma unroll
    for (int i = 0; i < 8; i++) { float t = S[lane + i * 64]; v[i] = t; s += t; s2 += t * t; }
    for (int o = 1; o < 64; o <<= 1) { s += __shfl_xor(s, o, 64); s2 += __shfl_xor(s2, o, 64); }
    float mu = s * (1.f / 512.f);
    float var = s2 * (1.f / 512.f) - mu * mu;
    float rs = rsqrtf(var + 1e-5f);
    float o0 = 0.f, o1 = 0.f;
    #pragma unroll
    for (int i = 0; i < 8; i++) {
        int j = lane + i * 64;
        float xn = (v[i] - mu) * rs * g[j] + b[j];
        o0 += xn * w[j * 2 + 0];
        o1 += xn * w[j * 2 + 1];
    }
    for (int o = 1; o < 64; o <<= 1) { o0 += __shfl_xor(o0, o, 64); o1 += __shfl_xor(o1, o, 64); }
    if (lane == 0) { out[0] = o0 + bb[0]; out[1] = o1 + bb[1]; }
}

__global__ void zerok(float* p, int n)
{
    int i = blockIdx.x * 256 + threadIdx.x;
    if (i < n) p[i] = 0.f;
}
__global__ void zero2k(float* p) { p[0] = 0.f; p[1] = 0.f; }
__global__ void copy512(float* dst, const float* src)
{
    int i = blockIdx.x * 256 + threadIdx.x;
    if (i < 512) dst[i] = src[i];
}

// ---------------------------------------------------------------------------
extern "C" void kernel_launch(void* const* d_in, const int* in_sizes, int n_in,
                              void* d_out, int out_size, void* d_ws, size_t ws_size,
                              hipStream_t stream)
{
    const float* h     = (const float*)d_in[0];
    const float* fc1_w = (const float*)d_in[1];
    const float* fc1_b = (const float*)d_in[2];
    const float* cls   = (const float*)d_in[3];
    // dict order (l1, l2, ppeg) vs signature order (l1, ppeg, l2)
    bool sigorder = (in_sizes[10] == 512 * 49);
    int i_l2 = sigorder ? 16 : 10;
    int i_pp = sigorder ? 10 : 16;
    const float* l_g[2]   = { (const float*)d_in[4], (const float*)d_in[i_l2 + 0] };
    const float* l_b[2]   = { (const float*)d_in[5], (const float*)d_in[i_l2 + 1] };
    const float* l_qkv[2] = { (const float*)d_in[6], (const float*)d_in[i_l2 + 2] };
    const float* l_ow[2]  = { (const float*)d_in[7], (const float*)d_in[i_l2 + 3] };
    const float* l_ob[2]  = { (const float*)d_in[8], (const float*)d_in[i_l2 + 4] };
    const float* l_rw[2]  = { (const float*)d_in[9], (const float*)d_in[i_l2 + 5] };
    const float* w7 = (const float*)d_in[i_pp + 0];
    const float* b7 = (const float*)d_in[i_pp + 1];
    const float* w5 = (const float*)d_in[i_pp + 2];
    const float* b5 = (const float*)d_in[i_pp + 3];
    const float* w3 = (const float*)d_in[i_pp + 4];
    const float* b3 = (const float*)d_in[i_pp + 5];
    const float* ng   = (const float*)d_in[22];
    const float* nbv  = (const float*)d_in[23];
    const float* fc2w = (const float*)d_in[24];
    const float* fc2b = (const float*)d_in[25];
    float* out = (float*)d_out;

    float* W = (float*)d_ws;
    size_t off = 0;
    auto alloc = [&](size_t n) { float* p = W + off; off += (n + 127) & ~(size_t)127; return p; };
    float* SEQ  = alloc((size_t)NSEQ * 512);
    float* XP   = alloc((size_t)LPAD * 512);
    float* QKV  = alloc((size_t)LPAD * 1536);
    float* QL   = alloc(131072);
    float* KL   = alloc(131072);
    float* A2   = alloc(524288);
    float* Zb   = alloc(524288);
    float* Z2b  = alloc(524288);
    float* XZ   = alloc(524288);
    float* W1   = alloc(524288);
    float* W2   = alloc(524288);
    float* W3b  = alloc(524288);
    float* A3V  = alloc(131072);
    float* ZMAT = alloc(131072);
    float* LSUM = alloc(2048);
    float* SCAL = alloc(16);
    float* W7T  = alloc(25088);
    float* W5T  = alloc(12800);
    float* W3T  = alloc(4608);
    size_t base_floats = off;
    bool batched = ws_size >= (base_floats + (size_t)8 * 256 * LPAD) * 4;
    float* SC = W + off;                // 84 MB batched, 10.5 MB per-head
    float* SEQ2 = QKV;                  // ppeg output aliases QKV (dead then)

    auto gemm = [&](const float* A, int lda, long sA, const float* B, int ldb, long sB,
                    float* C, int ldc, long sC, int M, int N, int K,
                    float alpha, float diagc, const float* bias,
                    const float* resid, int ldr,
                    const float* rowsc, int rs_stride,
                    int relu, int qscale, int btrans, int nbatch, int ksplit, int atomic) {
        dim3 grid(N / 64, (M + 63) / 64, nbatch * ksplit);
        gemm_big<<<grid, 256, 0, stream>>>(A, lda, sA, B, ldb, sB, C, ldc, sC, M, N, K,
            alpha, diagc, bias, resid, ldr, rowsc, rs_stride, relu, qscale, btrans,
            ksplit, atomic);
    };

    // fc1 + relu -> SEQ rows 1..10000 ; cls -> row 0 ; zero XP pad rows
    gemm(h, 1024, 0, fc1_w, 512, 0, SEQ + 512, 512, 0, NPIX, 512, 1024,
         1.f, 0.f, fc1_b, nullptr, 0, nullptr, 0, 1, 0, 0, 1, 1, 0);
    copy512<<<2, 256, 0, stream>>>(SEQ, cls);
    zerok<<<(PADT * 512 + 255) / 256, 256, 0, stream>>>(XP, PADT * 512);
    // ppeg weight transposes (used later)
    transpose_w<<<(512 * 49 + 255) / 256, 256, 0, stream>>>(w7, W7T, 49);
    transpose_w<<<(512 * 25 + 255) / 256, 256, 0, stream>>>(w5, W5T, 25);
    transpose_w<<<(512 * 9 + 255) / 256, 256, 0, stream>>>(w3, W3T, 9);

    for (int layer = 0; layer < 2; layer++) {
        const float* curSEQ = (layer == 0) ? SEQ : SEQ2;
        // LN -> XP rows [239, 10240)
        ln_kernel<<<(NSEQ + 3) / 4, 256, 0, stream>>>(curSEQ, XP + (size_t)PADT * 512,
                                                      l_g[layer], l_b[layer], NSEQ);
        // qkv projection (q scaled by 1/8 in epilogue)
        gemm(XP, 512, 0, l_qkv[layer], 1536, 0, QKV, 1536, 0, LPAD, 1536, 512,
             1.f, 0.f, nullptr, nullptr, 0, nullptr, 0, 0, 1, 0, 1, 1, 0);
        landmarks_kernel<<<dim3(256, 8), 64, 0, stream>>>(QKV, QL, KL);
        // a2 = softmax(ql @ kl^T)  (batched over heads, B transposed)
        gemm(QL, 64, 16384, KL, 64, 16384, A2, 256, 65536, 256, 256, 64,
             1.f, 0.f, nullptr, nullptr, 0, nullptr, 0, 0, 0, 1, 8, 1, 0);
        row_softmax<<<2048, 256, 0, stream>>>(A2, LSUM, 256, 1);
        // pinv denom + z0
        zero2k<<<1, 1, 0, stream>>>(SCAL);
        a2norms_kernel<<<8, 256, 0, stream>>>(A2, SCAL);
        z0_kernel<<<dim3(256, 8), 256, 0, stream>>>(A2, SCAL, Zb);
        // Newton-Schulz iterations
        float* zc = Zb; float* zn = Z2b;
        for (int it = 0; it < 6; it++) {
            gemm(A2, 256, 65536, zc, 256, 65536, XZ, 256, 65536, 256, 256, 256,
                 1.f, 0.f, nullptr, nullptr, 0, nullptr, 0, 0, 0, 0, 8, 1, 0);
            ew7_kernel<<<2048, 256, 0, stream>>>(XZ, W1);
            gemm(XZ, 256, 65536, W1, 256, 65536, W2, 256, 65536, 256, 256, 256,
                 -1.f, 15.f, nullptr, nullptr, 0, nullptr, 0, 0, 0, 0, 8, 1, 0);
            gemm(XZ, 256, 65536, W2, 256, 65536, W3b, 256, 65536, 256, 256, 256,
                 -1.f, 13.f, nullptr, nullptr, 0, nullptr, 0, 0, 0, 0, 8, 1, 0);
            gemm(zc, 256, 65536, W3b, 256, 65536, zn, 256, 65536, 256, 256, 256,
                 0.25f, 0.f, nullptr, nullptr, 0, nullptr, 0, 0, 0, 0, 8, 1, 0);
            float* t = zc; zc = zn; zn = t;
        }
        // a3v = softmax(ql @ k^T) @ v
        zerok<<<512, 256, 0, stream>>>(A3V, 131072);
        if (batched) {
            gemm(QL, 64, 16384, QKV + 512, 1536, 64, SC, LPAD, (long)256 * LPAD,
                 256, LPAD, 64, 1.f, 0.f, nullptr, nullptr, 0, nullptr, 0, 0, 0, 1, 8, 1, 0);
            row_softmax<<<2048, 256, 0, stream>>>(SC, LSUM, LPAD, 0);
            gemm(SC, LPAD, (long)256 * LPAD, QKV + 1024, 1536, 64, A3V, 64, 16384,
                 256, 64, LPAD, 1.f, 0.f, nullptr, nullptr, 0, LSUM, 256, 0, 0, 0, 8, 40, 1);
        } else {
            for (int hh = 0; hh < 8; hh++) {
                gemm(QL + (size_t)hh * 16384, 64, 0, QKV + 512 + hh * 64, 1536, 0,
                     SC, LPAD, 0, 256, LPAD, 64,
                     1.f, 0.f, nullptr, nullptr, 0, nullptr, 0, 0, 0, 1, 1, 1, 0);
                row_softmax<<<256, 256, 0, stream>>>(SC, LSUM, LPAD, 0);
                gemm(SC, LPAD, 0, QKV + 1024 + hh * 64, 1536, 0,
                     A3V + (size_t)hh * 16384, 64, 0, 256, 64, LPAD,
                     1.f, 0.f, nullptr, nullptr, 0, LSUM, 0, 0, 0, 0, 1, 40, 1);
            }
        }
        // ZMAT = pinv(a2) @ a3v
        gemm(zc, 256, 65536, A3V, 64, 16384, ZMAT, 64, 16384, 256, 64, 256,
             1.f, 0.f, nullptr, nullptr, 0, nullptr, 0, 0, 0, 0, 8, 1, 0);
        // fused a1 @ ZMAT + conv residual, in-place over q slice
        int nblk = (layer == 0) ? 313 : 1;     // layer 1: only token 239 needed
        a1z_conv<<<dim3(nblk, 8), 256, 0, stream>>>(QKV, KL, ZMAT, l_rw[layer], PADT);
        // out projection + bias + residual(LN'd x)
        int Mo = (layer == 0) ? NSEQ : 1;
        gemm(QKV + (size_t)PADT * 1536, 1536, 0, l_ow[layer], 512, 0, SEQ, 512, 0,
             Mo, 512, 512, 1.f, 0.f, l_ob[layer], XP + (size_t)PADT * 512, 512,
             nullptr, 0, 0, 0, 0, 1, 1, 0);
        if (layer == 0) {
            // PPEG: SEQ -> SEQ2
            ppeg_kernel<<<dim3(10000, 2), 256, 0, stream>>>(SEQ, SEQ2, W7T, b7, W5T, b5, W3T, b3);
            copy512<<<2, 256, 0, stream>>>(SEQ2, SEQ);   // cls passthrough
        }
    }
    final_kernel<<<1, 64, 0, stream>>>(SEQ, ng, nbv, fc2w, fc2b, out);
    (void)n_in; (void)out_size;
}

// Round 2
// 3052.284 us; speedup vs baseline: 2.3976x; 2.3976x over previous
//
#include <hip/hip_runtime.h>
#include <math.h>

#define LPAD  10240
#define NSEQ  10001
#define PADT  239
#define NPIX  10000

// ---------------------------------------------------------------------------
// Generic fp32 tiled GEMM: C = alpha*A@B (+diag) (+bias) (+resid) (*rowscale)
// 64x64 tile, 256 threads, 4x4 per-thread register tile. Supports:
//   - batch (grid.z strides), split-K with atomicAdd accumulate
//   - B transposed (B stored N x K row-major)
//   - qscale: multiply cols < 512 by 0.125 (q scaling inside qkv projection)
// ---------------------------------------------------------------------------
__global__ __launch_bounds__(256) void gemm_big(
    const float* __restrict__ A, int lda, long sA,
    const float* __restrict__ B, int ldb, long sB,
    float* __restrict__ C, int ldc, long sC,
    int M, int N, int K,
    float alpha, float diagc,
    const float* __restrict__ bias,
    const float* __restrict__ resid, int ldr,
    const float* __restrict__ rowscale, int rs_stride,
    int relu, int qscale, int btrans, int ksplit, int atomic)
{
    __shared__ float As[16][68];
    __shared__ float Bs[16][64];

    int bz = blockIdx.z / ksplit;
    int ks = blockIdx.z % ksplit;
    A += (size_t)bz * sA;
    B += (size_t)bz * sB;
    C += (size_t)bz * sC;

    int kchunk = (K + ksplit - 1) / ksplit;
    kchunk = (kchunk + 15) & ~15;
    int kbeg = ks * kchunk;
    int kend = kbeg + kchunk; if (kend > K) kend = K;

    int tid = threadIdx.x;
    int tx = tid & 15, ty = tid >> 4;
    int m0 = blockIdx.y * 64, n0 = blockIdx.x * 64;

    float acc[4][4];
    #pragma unroll
    for (int i = 0; i < 4; i++)
        #pragma unroll
        for (int j = 0; j < 4; j++) acc[i][j] = 0.f;

    for (int k0 = kbeg; k0 < kend; k0 += 16) {
        // A tile: 64 rows x 16 k
        {
            int r = tid >> 2;
            int kk = (tid & 3) * 4;
            int m = m0 + r;
            float4 av = make_float4(0.f, 0.f, 0.f, 0.f);
            if (m < M) av = *(const float4*)(A + (size_t)m * lda + k0 + kk);
            As[kk + 0][r] = av.x; As[kk + 1][r] = av.y;
            As[kk + 2][r] = av.z; As[kk + 3][r] = av.w;
        }
        // B tile: 16 k x 64 n
        if (!btrans) {
            int r = tid >> 6;      // 0..3
            int c = tid & 63;
            #pragma unroll
            for (int i = 0; i < 4; i++) {
                int kk = r + i * 4;
                Bs[kk][c] = B[(size_t)(k0 + kk) * ldb + n0 + c];
            }
        } else {
            int c = tid >> 2;      // 0..63
            int kk = (tid & 3) * 4;
            float4 bv = *(const float4*)(B + (size_t)(n0 + c) * ldb + k0 + kk);
            Bs[kk + 0][c] = bv.x; Bs[kk + 1][c] = bv.y;
            Bs[kk + 2][c] = bv.z; Bs[kk + 3][c] = bv.w;
        }
        __syncthreads();
        #pragma unroll
        for (int k = 0; k < 16; k++) {
            float4 a4 = *(const float4*)&As[k][ty * 4];
            float4 b4 = *(const float4*)&Bs[k][tx * 4];
            float a[4] = {a4.x, a4.y, a4.z, a4.w};
            float b[4] = {b4.x, b4.y, b4.z, b4.w};
            #pragma unroll
            for (int i = 0; i < 4; i++)
                #pragma unroll
                for (int j = 0; j < 4; j++) acc[i][j] += a[i] * b[j];
        }
        __syncthreads();
    }

    #pragma unroll
    for (int i = 0; i < 4; i++) {
        int m = m0 + ty * 4 + i;
        if (m >= M) continue;
        float rsc = rowscale ? rowscale[(size_t)bz * rs_stride + m] : 1.f;
        #pragma unroll
        for (int j = 0; j < 4; j++) {
            int n = n0 + tx * 4 + j;
            float v = alpha * acc[i][j];
            if (diagc != 0.f && m == n) v += diagc;
            if (qscale && n < 512) v *= 0.125f;
            if (bias) v += bias[n];
            if (resid) v += resid[(size_t)m * ldr + n];
            v *= rsc;
            if (relu) v = fmaxf(v, 0.f);
            float* cp = C + (size_t)m * ldc + n;
            if (atomic) atomicAdd(cp, v); else *cp = v;
        }
    }
}

// ---------------------------------------------------------------------------
// LayerNorm rows of 512: out = (x-mu)*rsqrt(var+1e-5)*g + b. 4 rows / block.
// ---------------------------------------------------------------------------
__global__ __launch_bounds__(256) void ln_kernel(
    const float* __restrict__ X, float* __restrict__ OUT,
    const float* __restrict__ g, const float* __restrict__ b, int nrows)
{
    int row = blockIdx.x * 4 + (threadIdx.x >> 6);
    int lane = threadIdx.x & 63;
    if (row >= nrows) return;
    const float* xr = X + (size_t)row * 512;
    float v[8]; float s = 0.f, s2 = 0.f;
    #pragma unroll
    for (int i = 0; i < 8; i++) { float t = xr[lane + i * 64]; v[i] = t; s += t; s2 += t * t; }
    for (int o = 1; o < 64; o <<= 1) { s += __shfl_xor(s, o, 64); s2 += __shfl_xor(s2, o, 64); }
    float mu = s * (1.f / 512.f);
    float var = s2 * (1.f / 512.f) - mu * mu;
    float rs = rsqrtf(var + 1e-5f);
    float* orow = OUT + (size_t)row * 512;
    #pragma unroll
    for (int i = 0; i < 8; i++) {
        int j = lane + i * 64;
        orow[j] = (v[i] - mu) * rs * g[j] + b[j];
    }
}

// ---------------------------------------------------------------------------
// Landmark means: ql[h][m][d] = mean_{li<40} q[m*40+li][h*64+d]; same for kl.
// ---------------------------------------------------------------------------
__global__ __launch_bounds__(64) void landmarks_kernel(
    const float* __restrict__ QKV, float* __restrict__ QL, float* __restrict__ KL)
{
    int mm = blockIdx.x, hh = blockIdx.y;
    int d = threadIdx.x;
    const float* base = QKV + (size_t)(mm * 40) * 1536 + hh * 64 + d;
    float sq = 0.f, sk = 0.f;
    for (int li = 0; li < 40; li++) {
        sq += base[(size_t)li * 1536];
        sk += base[(size_t)li * 1536 + 512];
    }
    QL[((size_t)hh * 256 + mm) * 64 + d] = sq * (1.f / 40.f);
    KL[((size_t)hh * 256 + mm) * 64 + d] = sk * (1.f / 40.f);
}

// ---------------------------------------------------------------------------
// Row softmax over ncols. norm=1: normalize in place. Always writes 1/sum.
// ---------------------------------------------------------------------------
__global__ __launch_bounds__(256) void row_softmax(
    float* __restrict__ S, float* __restrict__ LSUM, int ncols, int norm)
{
    int row = blockIdx.x;
    float* p = S + (size_t)row * ncols;
    int tid = threadIdx.x;
    __shared__ float sr1[4], sr2[4];
    float mx = -1e30f;
    for (int i = tid; i < ncols; i += 256) mx = fmaxf(mx, p[i]);
    for (int o = 1; o < 64; o <<= 1) mx = fmaxf(mx, __shfl_xor(mx, o, 64));
    if ((tid & 63) == 0) sr1[tid >> 6] = mx;
    __syncthreads();
    mx = fmaxf(fmaxf(sr1[0], sr1[1]), fmaxf(sr1[2], sr1[3]));
    float s = 0.f;
    for (int i = tid; i < ncols; i += 256) { float e = __expf(p[i] - mx); p[i] = e; s += e; }
    for (int o = 1; o < 64; o <<= 1) s += __shfl_xor(s, o, 64);
    if ((tid & 63) == 0) sr2[tid >> 6] = s;
    __syncthreads();
    s = sr2[0] + sr2[1] + sr2[2] + sr2[3];
    float inv = 1.f / s;
    if (tid == 0) LSUM[row] = inv;
    if (norm) for (int i = tid; i < ncols; i += 256) p[i] *= inv;
}

// ---------------------------------------------------------------------------
// Global pinv denom: scal[0]=max row |sum|, scal[1]=max col |sum| (across heads)
// ---------------------------------------------------------------------------
__global__ __launch_bounds__(256) void a2norms_kernel(
    const float* __restrict__ A2, float* __restrict__ scal)
{
    int hh = blockIdx.x, tid = threadIdx.x;
    const float* A = A2 + (size_t)hh * 65536;
    float rs = 0.f, cs = 0.f;
    for (int j = 0; j < 256; j++) {
        rs += fabsf(A[(size_t)tid * 256 + j]);
        cs += fabsf(A[(size_t)j * 256 + tid]);
    }
    __shared__ float sm[8];
    for (int o = 1; o < 64; o <<= 1) {
        rs = fmaxf(rs, __shfl_xor(rs, o, 64));
        cs = fmaxf(cs, __shfl_xor(cs, o, 64));
    }
    if ((tid & 63) == 0) { sm[tid >> 6] = rs; sm[4 + (tid >> 6)] = cs; }
    __syncthreads();
    if (tid == 0) {
        float rm = fmaxf(fmaxf(sm[0], sm[1]), fmaxf(sm[2], sm[3]));
        float cm = fmaxf(fmaxf(sm[4], sm[5]), fmaxf(sm[6], sm[7]));
        atomicMax((unsigned int*)&scal[0], __float_as_uint(rm));
        atomicMax((unsigned int*)&scal[1], __float_as_uint(cm));
    }
}

// z0 = a2^T / (rowmax*colmax)
__global__ __launch_bounds__(256) void z0_kernel(
    const float* __restrict__ A2, const float* __restrict__ scal, float* __restrict__ Z)
{
    int i = blockIdx.x, hh = blockIdx.y, j = threadIdx.x;
    float inv = 1.f / (scal[0] * scal[1]);
    Z[((size_t)hh * 256 + i) * 256 + j] = A2[((size_t)hh * 256 + j) * 256 + i] * inv;
}

// W1 = 7I - XZ
__global__ __launch_bounds__(256) void ew7_kernel(
    const float* __restrict__ XZ, float* __restrict__ W1)
{
    size_t idx = (size_t)blockIdx.x * 256 + threadIdx.x;
    if (idx >= (size_t)8 * 65536) return;
    int within = (int)(idx & 65535);
    int i = within >> 8, j = within & 255;
    W1[idx] = ((i == j) ? 7.f : 0.f) - XZ[idx];
}

// ---------------------------------------------------------------------------
// a1 @ Z, in-place over q slice of QKV (conv residual split into conv_res).
// Block: 32 tokens x 1 head. Thread (li=tid>>3, g=tid&7).
// ---------------------------------------------------------------------------
__global__ __launch_bounds__(256) void a1z(
    float* __restrict__ QKV,
    const float* __restrict__ KLg,
    const float* __restrict__ ZMg,
    int T0)
{
    int hh = blockIdx.y;
    int t0 = T0 + blockIdx.x * 32;
    int tid = threadIdx.x;
    int li = tid >> 3, g = tid & 7;
    int tok = t0 + li;
    bool valid = tok < LPAD;

    __shared__ float qs[32][68];
    __shared__ float kz[64][68];
    __shared__ float sb[32][260];

    {
        const float* qp = QKV + (size_t)(valid ? tok : 0) * 1536 + hh * 64 + g * 8;
        float4 v0 = make_float4(0.f, 0.f, 0.f, 0.f), v1 = v0;
        if (valid) { v0 = *(const float4*)qp; v1 = *(const float4*)(qp + 4); }
        *(float4*)&qs[li][g * 8] = v0;
        *(float4*)&qs[li][g * 8 + 4] = v1;
    }
    // scores: 256 landmark cols in 4 chunks of 64
    for (int c = 0; c < 4; c++) {
        __syncthreads();
        {
            int j = tid >> 2, cc = (tid & 3) * 16;
            const float* kp = KLg + ((size_t)hh * 256 + c * 64 + j) * 64 + cc;
            #pragma unroll
            for (int i = 0; i < 16; i += 4)
                *(float4*)&kz[j][cc + i] = *(const float4*)(kp + i);
        }
        __syncthreads();
        #pragma unroll
        for (int jj = 0; jj < 8; jj++) {
            int j = g + jj * 8;           // stride-8 mapping: conflict-free banks
            float d = 0.f;
            #pragma unroll
            for (int k = 0; k < 64; k += 4) {
                float4 a = *(const float4*)&qs[li][k];
                float4 b = *(const float4*)&kz[j][k];
                d += a.x * b.x + a.y * b.y + a.z * b.z + a.w * b.w;
            }
            sb[li][c * 64 + j] = d;
        }
    }
    __syncthreads();
    // softmax over row (256)
    float mx = -1e30f;
    for (int t = 0; t < 32; t++) mx = fmaxf(mx, sb[li][g * 32 + t]);
    for (int o = 1; o < 8; o <<= 1) mx = fmaxf(mx, __shfl_xor(mx, o, 64));
    float ls = 0.f;
    for (int t = 0; t < 32; t++) {
        float e = __expf(sb[li][g * 32 + t] - mx);
        sb[li][g * 32 + t] = e; ls += e;
    }
    for (int o = 1; o < 8; o <<= 1) ls += __shfl_xor(ls, o, 64);
    float invl = 1.f / ls;
    // matvec with Z (256 x 64)
    float acc[8] = {0.f, 0.f, 0.f, 0.f, 0.f, 0.f, 0.f, 0.f};
    for (int c = 0; c < 4; c++) {
        __syncthreads();
        {
            int j = tid >> 2, cc = (tid & 3) * 16;
            const float* zp = ZMg + ((size_t)hh * 256 + c * 64 + j) * 64 + cc;
            #pragma unroll
            for (int i = 0; i < 16; i += 4)
                *(float4*)&kz[j][cc + i] = *(const float4*)(zp + i);
        }
        __syncthreads();
        #pragma unroll 4
        for (int j = 0; j < 64; j++) {
            float p = sb[li][c * 64 + j];
            float4 z0 = *(const float4*)&kz[j][g * 8];
            float4 z1 = *(const float4*)&kz[j][g * 8 + 4];
            acc[0] += p * z0.x; acc[1] += p * z0.y; acc[2] += p * z0.z; acc[3] += p * z0.w;
            acc[4] += p * z1.x; acc[5] += p * z1.y; acc[6] += p * z1.z; acc[7] += p * z1.w;
        }
    }
    if (valid) {
        float* op = QKV + (size_t)tok * 1536 + hh * 64 + g * 8;
        *(float4*)op = make_float4(acc[0] * invl, acc[1] * invl,
                                   acc[2] * invl, acc[3] * invl);
        *(float4*)(op + 4) = make_float4(acc[4] * invl, acc[5] * invl,
                                         acc[6] * invl, acc[7] * invl);
    }
}

// ---------------------------------------------------------------------------
// Depthwise 33-tap token conv of V slice, added into q slice (after a1z).
// Thread = (token, channel). Coalesced across channels; sliding-window V rows
// are L2-resident.
// ---------------------------------------------------------------------------
__global__ __launch_bounds__(256) void conv_res(
    float* __restrict__ QKV, const float* __restrict__ resw, int t0, int ntok)
{
    int idx = blockIdx.x * 256 + threadIdx.x;
    if (idx >= ntok * 512) return;
    int tok = t0 + (idx >> 9);
    int c = idx & 511;
    int h = c >> 6;
    const float* vbase = QKV + 1024 + c;
    float acc = 0.f;
    #pragma unroll 1
    for (int r = 0; r < 33; r++) {
        int ts = tok - 16 + r;
        if (ts >= 0 && ts < LPAD)
            acc += resw[h * 33 + r] * vbase[(size_t)ts * 1536];
    }
    QKV[(size_t)tok * 1536 + c] += acc;
}

// ---------------------------------------------------------------------------
// PPEG: y = (dw7+b7) + f + (dw5+b5) + (dw3+b3), 100x100, 512 ch, zero pad.
// Weights pre-transposed to [tap][512].
// ---------------------------------------------------------------------------
__global__ __launch_bounds__(256) void ppeg_kernel(
    const float* __restrict__ S, float* __restrict__ O,
    const float* __restrict__ w7t, const float* __restrict__ b7,
    const float* __restrict__ w5t, const float* __restrict__ b5,
    const float* __restrict__ w3t, const float* __restrict__ b3)
{
    int pos = blockIdx.x;
    int y = pos / 100, x = pos - y * 100;
    int c = blockIdx.y * 256 + threadIdx.x;
    float acc = S[(size_t)(1 + pos) * 512 + c] + b7[c] + b5[c] + b3[c];
    for (int dy = -3; dy <= 3; dy++) {
        int yy = y + dy; if ((unsigned)yy >= 100u) continue;
        for (int dx = -3; dx <= 3; dx++) {
            int xx = x + dx; if ((unsigned)xx >= 100u) continue;
            float v = S[(size_t)(1 + yy * 100 + xx) * 512 + c];
            float wsum = w7t[((dy + 3) * 7 + (dx + 3)) * 512 + c];
            if (dy >= -2 && dy <= 2 && dx >= -2 && dx <= 2)
                wsum += w5t[((dy + 2) * 5 + (dx + 2)) * 512 + c];
            if (dy >= -1 && dy <= 1 && dx >= -1 && dx <= 1)
                wsum += w3t[((dy + 1) * 3 + (dx + 1)) * 512 + c];
            acc += v * wsum;
        }
    }
    O[(size_t)(1 + pos) * 512 + c] = acc;
}

__global__ void transpose_w(const float* __restrict__ w, float* __restrict__ wt, int KK)
{
    int idx = blockIdx.x * 256 + threadIdx.x;
    if (idx >= 512 * KK) return;
    int c = idx / KK, k = idx - c * KK;
    wt[k * 512 + c] = w[idx];
}

// Final: LN(token0) @ fc2_w + fc2_b
__global__ __launch_bounds__(64) void final_kernel(
    const float* __restrict__ S, const float* __restrict__ g, const float* __restrict__ b,
    const float* __restrict__ w, const float* __restrict__ bb, float* __restrict__ out)
{
    int lane = threadIdx.x;
    float v[8]; float s = 0.f, s2 = 0.f;
    #pragma unroll
    for (int i = 0; i < 8; i++) { float t = S[lane + i * 64]; v[i] = t; s += t; s2 += t * t; }
    for (int o = 1; o < 64; o <<= 1) { s += __shfl_xor(s, o, 64); s2 += __shfl_xor(s2, o, 64); }
    float mu = s * (1.f / 512.f);
    float var = s2 * (1.f / 512.f) - mu * mu;
    float rs = rsqrtf(var + 1e-5f);
    float o0 = 0.f, o1 = 0.f;
    #pragma unroll
    for (int i = 0; i < 8; i++) {
        int j = lane + i * 64;
        float xn = (v[i] - mu) * rs * g[j] + b[j];
        o0 += xn * w[j * 2 + 0];
        o1 += xn * w[j * 2 + 1];
    }
    for (int o = 1; o < 64; o <<= 1) { o0 += __shfl_xor(o0, o, 64); o1 += __shfl_xor(o1, o, 64); }
    if (lane == 0) { out[0] = o0 + bb[0]; out[1] = o1 + bb[1]; }
}

__global__ void zerok(float* p, int n)
{
    int i = blockIdx.x * 256 + threadIdx.x;
    if (i < n) p[i] = 0.f;
}
__global__ void zero2k(float* p) { p[0] = 0.f; p[1] = 0.f; }
__global__ void copy512(float* dst, const float* src)
{
    int i = blockIdx.x * 256 + threadIdx.x;
    if (i < 512) dst[i] = src[i];
}

// ---------------------------------------------------------------------------
extern "C" void kernel_launch(void* const* d_in, const int* in_sizes, int n_in,
                              void* d_out, int out_size, void* d_ws, size_t ws_size,
                              hipStream_t stream)
{
    const float* h     = (const float*)d_in[0];
    const float* fc1_w = (const float*)d_in[1];
    const float* fc1_b = (const float*)d_in[2];
    const float* cls   = (const float*)d_in[3];
    // dict order (l1, l2, ppeg) vs signature order (l1, ppeg, l2)
    bool sigorder = (in_sizes[10] == 512 * 49);
    int i_l2 = sigorder ? 16 : 10;
    int i_pp = sigorder ? 10 : 16;
    const float* l_g[2]   = { (const float*)d_in[4], (const float*)d_in[i_l2 + 0] };
    const float* l_b[2]   = { (const float*)d_in[5], (const float*)d_in[i_l2 + 1] };
    const float* l_qkv[2] = { (const float*)d_in[6], (const float*)d_in[i_l2 + 2] };
    const float* l_ow[2]  = { (const float*)d_in[7], (const float*)d_in[i_l2 + 3] };
    const float* l_ob[2]  = { (const float*)d_in[8], (const float*)d_in[i_l2 + 4] };
    const float* l_rw[2]  = { (const float*)d_in[9], (const float*)d_in[i_l2 + 5] };
    const float* w7 = (const float*)d_in[i_pp + 0];
    const float* b7 = (const float*)d_in[i_pp + 1];
    const float* w5 = (const float*)d_in[i_pp + 2];
    const float* b5 = (const float*)d_in[i_pp + 3];
    const float* w3 = (const float*)d_in[i_pp + 4];
    const float* b3 = (const float*)d_in[i_pp + 5];
    const float* ng   = (const float*)d_in[22];
    const float* nbv  = (const float*)d_in[23];
    const float* fc2w = (const float*)d_in[24];
    const float* fc2b = (const float*)d_in[25];
    float* out = (float*)d_out;

    float* W = (float*)d_ws;
    size_t off = 0;
    auto alloc = [&](size_t n) { float* p = W + off; off += (n + 127) & ~(size_t)127; return p; };
    float* SEQ  = alloc((size_t)NSEQ * 512);
    float* XP   = alloc((size_t)LPAD * 512);
    float* QKV  = alloc((size_t)LPAD * 1536);
    float* QL   = alloc(131072);
    float* KL   = alloc(131072);
    float* A2   = alloc(524288);
    float* Zb   = alloc(524288);
    float* Z2b  = alloc(524288);
    float* XZ   = alloc(524288);
    float* W1   = alloc(524288);
    float* W2   = alloc(524288);
    float* W3b  = alloc(524288);
    float* A3V  = alloc(131072);
    float* ZMAT = alloc(131072);
    float* LSUM = alloc(2048);
    float* SCAL = alloc(16);
    float* W7T  = alloc(25088);
    float* W5T  = alloc(12800);
    float* W3T  = alloc(4608);
    size_t base_floats = off;
    bool batched = ws_size >= (base_floats + (size_t)8 * 256 * LPAD) * 4;
    float* SC = W + off;                // 84 MB batched, 10.5 MB per-head
    float* SEQ2 = QKV;                  // ppeg output aliases QKV (dead then)

    auto gemm = [&](const float* A, int lda, long sA, const float* B, int ldb, long sB,
                    float* C, int ldc, long sC, int M, int N, int K,
                    float alpha, float diagc, const float* bias,
                    const float* resid, int ldr,
                    const float* rowsc, int rs_stride,
                    int relu, int qscale, int btrans, int nbatch, int ksplit, int atomic) {
        dim3 grid(N / 64, (M + 63) / 64, nbatch * ksplit);
        gemm_big<<<grid, 256, 0, stream>>>(A, lda, sA, B, ldb, sB, C, ldc, sC, M, N, K,
            alpha, diagc, bias, resid, ldr, rowsc, rs_stride, relu, qscale, btrans,
            ksplit, atomic);
    };

    // fc1 + relu -> SEQ rows 1..10000 ; cls -> row 0 ; zero XP pad rows
    gemm(h, 1024, 0, fc1_w, 512, 0, SEQ + 512, 512, 0, NPIX, 512, 1024,
         1.f, 0.f, fc1_b, nullptr, 0, nullptr, 0, 1, 0, 0, 1, 1, 0);
    copy512<<<2, 256, 0, stream>>>(SEQ, cls);
    zerok<<<(PADT * 512 + 255) / 256, 256, 0, stream>>>(XP, PADT * 512);
    // ppeg weight transposes (used later)
    transpose_w<<<(512 * 49 + 255) / 256, 256, 0, stream>>>(w7, W7T, 49);
    transpose_w<<<(512 * 25 + 255) / 256, 256, 0, stream>>>(w5, W5T, 25);
    transpose_w<<<(512 * 9 + 255) / 256, 256, 0, stream>>>(w3, W3T, 9);

    for (int layer = 0; layer < 2; layer++) {
        const float* curSEQ = (layer == 0) ? SEQ : SEQ2;
        // LN -> XP rows [239, 10240)
        ln_kernel<<<(NSEQ + 3) / 4, 256, 0, stream>>>(curSEQ, XP + (size_t)PADT * 512,
                                                      l_g[layer], l_b[layer], NSEQ);
        // qkv projection (q scaled by 1/8 in epilogue)
        gemm(XP, 512, 0, l_qkv[layer], 1536, 0, QKV, 1536, 0, LPAD, 1536, 512,
             1.f, 0.f, nullptr, nullptr, 0, nullptr, 0, 0, 1, 0, 1, 1, 0);
        landmarks_kernel<<<dim3(256, 8), 64, 0, stream>>>(QKV, QL, KL);
        // a2 = softmax(ql @ kl^T)  (batched over heads, B transposed)
        gemm(QL, 64, 16384, KL, 64, 16384, A2, 256, 65536, 256, 256, 64,
             1.f, 0.f, nullptr, nullptr, 0, nullptr, 0, 0, 0, 1, 8, 1, 0);
        row_softmax<<<2048, 256, 0, stream>>>(A2, LSUM, 256, 1);
        // pinv denom + z0
        zero2k<<<1, 1, 0, stream>>>(SCAL);
        a2norms_kernel<<<8, 256, 0, stream>>>(A2, SCAL);
        z0_kernel<<<dim3(256, 8), 256, 0, stream>>>(A2, SCAL, Zb);
        // Newton-Schulz iterations
        float* zc = Zb; float* zn = Z2b;
        for (int it = 0; it < 6; it++) {
            gemm(A2, 256, 65536, zc, 256, 65536, XZ, 256, 65536, 256, 256, 256,
                 1.f, 0.f, nullptr, nullptr, 0, nullptr, 0, 0, 0, 0, 8, 1, 0);
            ew7_kernel<<<2048, 256, 0, stream>>>(XZ, W1);
            gemm(XZ, 256, 65536, W1, 256, 65536, W2, 256, 65536, 256, 256, 256,
                 -1.f, 15.f, nullptr, nullptr, 0, nullptr, 0, 0, 0, 0, 8, 1, 0);
            gemm(XZ, 256, 65536, W2, 256, 65536, W3b, 256, 65536, 256, 256, 256,
                 -1.f, 13.f, nullptr, nullptr, 0, nullptr, 0, 0, 0, 0, 8, 1, 0);
            gemm(zc, 256, 65536, W3b, 256, 65536, zn, 256, 65536, 256, 256, 256,
                 0.25f, 0.f, nullptr, nullptr, 0, nullptr, 0, 0, 0, 0, 8, 1, 0);
            float* t = zc; zc = zn; zn = t;
        }
        // a3v = softmax(ql @ k^T) @ v
        zerok<<<512, 256, 0, stream>>>(A3V, 131072);
        if (batched) {
            gemm(QL, 64, 16384, QKV + 512, 1536, 64, SC, LPAD, (long)256 * LPAD,
                 256, LPAD, 64, 1.f, 0.f, nullptr, nullptr, 0, nullptr, 0, 0, 0, 1, 8, 1, 0);
            row_softmax<<<2048, 256, 0, stream>>>(SC, LSUM, LPAD, 0);
            gemm(SC, LPAD, (long)256 * LPAD, QKV + 1024, 1536, 64, A3V, 64, 16384,
                 256, 64, LPAD, 1.f, 0.f, nullptr, nullptr, 0, LSUM, 256, 0, 0, 0, 8, 40, 1);
        } else {
            for (int hh = 0; hh < 8; hh++) {
                gemm(QL + (size_t)hh * 16384, 64, 0, QKV + 512 + hh * 64, 1536, 0,
                     SC, LPAD, 0, 256, LPAD, 64,
                     1.f, 0.f, nullptr, nullptr, 0, nullptr, 0, 0, 0, 1, 1, 1, 0);
                row_softmax<<<256, 256, 0, stream>>>(SC, LSUM, LPAD, 0);
                gemm(SC, LPAD, 0, QKV + 1024 + hh * 64, 1536, 0,
                     A3V + (size_t)hh * 16384, 64, 0, 256, 64, LPAD,
                     1.f, 0.f, nullptr, nullptr, 0, LSUM, 0, 0, 0, 0, 1, 40, 1);
            }
        }
        // ZMAT = pinv(a2) @ a3v
        gemm(zc, 256, 65536, A3V, 64, 16384, ZMAT, 64, 16384, 256, 64, 256,
             1.f, 0.f, nullptr, nullptr, 0, nullptr, 0, 0, 0, 0, 8, 1, 0);
        // a1 @ ZMAT in-place over q slice, then depthwise conv residual add
        int nblk = (layer == 0) ? 313 : 1;     // layer 1: only token 239 needed
        a1z<<<dim3(nblk, 8), 256, 0, stream>>>(QKV, KL, ZMAT, PADT);
        int ntok = (layer == 0) ? NSEQ : 1;
        conv_res<<<(ntok * 512 + 255) / 256, 256, 0, stream>>>(QKV, l_rw[layer], PADT, ntok);
        // out projection + bias + residual(LN'd x)
        int Mo = (layer == 0) ? NSEQ : 1;
        gemm(QKV + (size_t)PADT * 1536, 1536, 0, l_ow[layer], 512, 0, SEQ, 512, 0,
             Mo, 512, 512, 1.f, 0.f, l_ob[layer], XP + (size_t)PADT * 512, 512,
             nullptr, 0, 0, 0, 0, 1, 1, 0);
        if (layer == 0) {
            // PPEG: SEQ -> SEQ2
            ppeg_kernel<<<dim3(10000, 2), 256, 0, stream>>>(SEQ, SEQ2, W7T, b7, W5T, b5, W3T, b3);
            copy512<<<2, 256, 0, stream>>>(SEQ2, SEQ);   // cls passthrough
        }
    }
    final_kernel<<<1, 64, 0, stream>>>(SEQ, ng, nbv, fc2w, fc2b, out);
    (void)n_in; (void)out_size;
}

// Round 3
// 2210.694 us; speedup vs baseline: 3.3104x; 1.3807x over previous
//
#include <hip/hip_runtime.h>
#include <math.h>

#define LPAD  10240
#define NSEQ  10001
#define PADT  239
#define NPIX  10000

typedef unsigned short u16;
typedef __attribute__((ext_vector_type(8))) short short8;
typedef __attribute__((ext_vector_type(4))) float floatx4;

__device__ __forceinline__ float b2f(u16 u){ return __uint_as_float(((unsigned)u)<<16); }
__device__ __forceinline__ u16 f2b(float f){
    unsigned x = __float_as_uint(f);
    return (u16)((x + 0x7FFFu + ((x>>16)&1u)) >> 16);
}
__device__ __forceinline__ void gld16(const void* g, void* l){
    __builtin_amdgcn_global_load_lds(
        (const __attribute__((address_space(1))) unsigned int*)g,
        (__attribute__((address_space(3))) unsigned int*)l, 16, 0, 0);
}

// ---------------------------------------------------------------------------
// bf16 MFMA GEMM: C = A @ Bt^T (+bias)(+resid)(relu)(qscale). A: M x K bf16
// row-major (lda, batch sA). Bt: N x K bf16 (ldb, sB). C fp32 or bf16 (obf16),
// ldc/sC, optional split-K with fp32 atomicAdd. 128x128 tile, 4 waves,
// 16x16x32 MFMA, global_load_lds width-16 staging (m97 structure).
// Rows >= M / cols >= N are clamped on load (affect only unstored C tiles).
// ---------------------------------------------------------------------------
__global__ __launch_bounds__(256) void gemm_mfma(
    const u16* __restrict__ A, int lda, long sA,
    const u16* __restrict__ Bt, int ldb, long sB,
    void* __restrict__ Cv, int ldc, long sC,
    int M, int N, int K, int ksplit,
    const float* __restrict__ bias,
    const float* __restrict__ resid, int ldr,
    int relu, int qscale, int obf16, int atomic)
{
    __shared__ u16 As[128*32];
    __shared__ u16 Bs[128*32];

    int bz = blockIdx.z / ksplit;
    int ks = blockIdx.z - bz * ksplit;
    A  += (size_t)bz * sA;
    Bt += (size_t)bz * sB;

    int kchunk = (K + ksplit - 1) / ksplit;
    kchunk = (kchunk + 31) & ~31;
    int kbeg = ks * kchunk;
    int kend = kbeg + kchunk; if (kend > K) kend = K;

    int tid = threadIdx.x;
    int w = tid >> 6, lane = tid & 63;
    int wm = (w >> 1) * 64, wn = (w & 1) * 64;
    int m0 = blockIdx.y * 128, n0 = blockIdx.x * 128;

    // staging: wave w fills tile rows [w*32, w*32+32) for A and B
    int l4 = lane >> 2;            // 0..15
    int lk = (lane & 3) * 8;       // k elem offset (16B granule)
    int r0 = w * 32 + l4;
    int am0 = m0 + r0;      if (am0 > M-1) am0 = M-1;
    int am1 = m0 + r0 + 16; if (am1 > M-1) am1 = M-1;
    int bn0 = n0 + r0;      if (bn0 > N-1) bn0 = N-1;
    int bn1 = n0 + r0 + 16; if (bn1 > N-1) bn1 = N-1;
    const u16* ag0 = A  + (size_t)am0 * lda + lk;
    const u16* ag1 = A  + (size_t)am1 * lda + lk;
    const u16* bg0 = Bt + (size_t)bn0 * ldb + lk;
    const u16* bg1 = Bt + (size_t)bn1 * ldb + lk;
    u16* al0 = &As[(w*32)      * 32];
    u16* al1 = &As[(w*32 + 16) * 32];
    u16* bl0 = &Bs[(w*32)      * 32];
    u16* bl1 = &Bs[(w*32 + 16) * 32];

    floatx4 acc[4][4];
    #pragma unroll
    for (int i = 0; i < 4; i++)
        #pragma unroll
        for (int j = 0; j < 4; j++)
            acc[i][j] = (floatx4){0.f, 0.f, 0.f, 0.f};

    int arow = wm + (lane & 15);
    int nrow = wn + (lane & 15);
    int koff = (lane >> 4) * 8;

    for (int k0 = kbeg; k0 < kend; k0 += 32) {
        gld16(ag0 + k0, al0);
        gld16(ag1 + k0, al1);
        gld16(bg0 + k0, bl0);
        gld16(bg1 + k0, bl1);
        __syncthreads();
        short8 af[4], bf[4];
        #pragma unroll
        for (int i = 0; i < 4; i++) af[i] = *(const short8*)&As[(arow + i*16)*32 + koff];
        #pragma unroll
        for (int j = 0; j < 4; j++) bf[j] = *(const short8*)&Bs[(nrow + j*16)*32 + koff];
        #pragma unroll
        for (int i = 0; i < 4; i++)
            #pragma unroll
            for (int j = 0; j < 4; j++)
                acc[i][j] = __builtin_amdgcn_mfma_f32_16x16x32_bf16(af[i], bf[j], acc[i][j], 0, 0, 0);
        __syncthreads();
    }

    float* Cf = (float*)Cv;
    u16*   Ch = (u16*)Cv;
    size_t cb = (size_t)bz * sC;
    int rbase = m0 + wm + (lane >> 4) * 4;
    int cbase = n0 + wn + (lane & 15);
    #pragma unroll
    for (int i = 0; i < 4; i++) {
        #pragma unroll
        for (int j = 0; j < 4; j++) {
            int col = cbase + j * 16;
            if (col >= N) continue;
            float bcol = bias ? bias[col] : 0.f;
            #pragma unroll
            for (int r = 0; r < 4; r++) {
                int row = rbase + i * 16 + r;
                if (row >= M) continue;
                float v = acc[i][j][r];
                if (qscale && col < 512) v *= 0.125f;
                v += bcol;
                if (resid) v += resid[(size_t)row * ldr + col];
                if (relu) v = fmaxf(v, 0.f);
                size_t ci = cb + (size_t)row * ldc + col;
                if (obf16) Ch[ci] = f2b(v);
                else if (atomic) atomicAdd(&Cf[ci], v);
                else Cf[ci] = v;
            }
        }
    }
}

// ---------------------------------------------------------------------------
// fp32 tiled GEMM (kept for the numerically-sensitive Newton-Schulz chain and
// tiny gemms). C = alpha*A@B + diagc*I + rescoef*resid + bias.
// ---------------------------------------------------------------------------
__global__ __launch_bounds__(256) void gemm_big(
    const float* __restrict__ A, int lda, long sA,
    const float* __restrict__ B, int ldb, long sB,
    float* __restrict__ C, int ldc, long sC,
    int M, int N, int K,
    float alpha, float diagc,
    const float* __restrict__ bias,
    const float* __restrict__ resid, int ldr, long sR, float rescoef,
    int btrans)
{
    __shared__ float As[16][68];
    __shared__ float Bs[16][64];

    int bz = blockIdx.z;
    A += (size_t)bz * sA;
    B += (size_t)bz * sB;
    C += (size_t)bz * sC;

    int tid = threadIdx.x;
    int tx = tid & 15, ty = tid >> 4;
    int m0 = blockIdx.y * 64, n0 = blockIdx.x * 64;

    float acc[4][4];
    #pragma unroll
    for (int i = 0; i < 4; i++)
        #pragma unroll
        for (int j = 0; j < 4; j++) acc[i][j] = 0.f;

    for (int k0 = 0; k0 < K; k0 += 16) {
        {
            int r = tid >> 2;
            int kk = (tid & 3) * 4;
            int m = m0 + r;
            float4 av = make_float4(0.f, 0.f, 0.f, 0.f);
            if (m < M) av = *(const float4*)(A + (size_t)m * lda + k0 + kk);
            As[kk + 0][r] = av.x; As[kk + 1][r] = av.y;
            As[kk + 2][r] = av.z; As[kk + 3][r] = av.w;
        }
        if (!btrans) {
            int r = tid >> 6;
            int c = tid & 63;
            #pragma unroll
            for (int i = 0; i < 4; i++) {
                int kk = r + i * 4;
                Bs[kk][c] = B[(size_t)(k0 + kk) * ldb + n0 + c];
            }
        } else {
            int c = tid >> 2;
            int kk = (tid & 3) * 4;
            float4 bv = *(const float4*)(B + (size_t)(n0 + c) * ldb + k0 + kk);
            Bs[kk + 0][c] = bv.x; Bs[kk + 1][c] = bv.y;
            Bs[kk + 2][c] = bv.z; Bs[kk + 3][c] = bv.w;
        }
        __syncthreads();
        #pragma unroll
        for (int k = 0; k < 16; k++) {
            float4 a4 = *(const float4*)&As[k][ty * 4];
            float4 b4 = *(const float4*)&Bs[k][tx * 4];
            float a[4] = {a4.x, a4.y, a4.z, a4.w};
            float b[4] = {b4.x, b4.y, b4.z, b4.w};
            #pragma unroll
            for (int i = 0; i < 4; i++)
                #pragma unroll
                for (int j = 0; j < 4; j++) acc[i][j] += a[i] * b[j];
        }
        __syncthreads();
    }

    #pragma unroll
    for (int i = 0; i < 4; i++) {
        int m = m0 + ty * 4 + i;
        if (m >= M) continue;
        #pragma unroll
        for (int j = 0; j < 4; j++) {
            int n = n0 + tx * 4 + j;
            float v = alpha * acc[i][j];
            if (diagc != 0.f && m == n) v += diagc;
            if (bias) v += bias[n];
            if (resid) v += rescoef * resid[(size_t)bz * sR + (size_t)m * ldr + n];
            C[(size_t)m * ldc + n] = v;
        }
    }
}

// ---------------------------------------------------------------------------
__global__ __launch_bounds__(256) void ln_kernel(
    const float* __restrict__ X, float* __restrict__ OUT, u16* __restrict__ OUTH,
    const float* __restrict__ g, const float* __restrict__ b, int nrows)
{
    int row = blockIdx.x * 4 + (threadIdx.x >> 6);
    int lane = threadIdx.x & 63;
    if (row >= nrows) return;
    const float* xr = X + (size_t)row * 512;
    float v[8]; float s = 0.f, s2 = 0.f;
    #pragma unroll
    for (int i = 0; i < 8; i++) { float t = xr[lane + i * 64]; v[i] = t; s += t; s2 += t * t; }
    for (int o = 1; o < 64; o <<= 1) { s += __shfl_xor(s, o, 64); s2 += __shfl_xor(s2, o, 64); }
    float mu = s * (1.f / 512.f);
    float var = s2 * (1.f / 512.f) - mu * mu;
    float rs = rsqrtf(var + 1e-5f);
    float* orow = OUT + (size_t)row * 512;
    u16* hrow = OUTH + (size_t)row * 512;
    #pragma unroll
    for (int i = 0; i < 8; i++) {
        int j = lane + i * 64;
        float y = (v[i] - mu) * rs * g[j] + b[j];
        orow[j] = y;
        hrow[j] = f2b(y);
    }
}

// Landmark means from bf16 QKVh
__global__ __launch_bounds__(64) void landmarks_kernel(
    const u16* __restrict__ QKVh, float* __restrict__ QL, float* __restrict__ KL)
{
    int mm = blockIdx.x, hh = blockIdx.y;
    int d = threadIdx.x;
    const u16* base = QKVh + (size_t)(mm * 40) * 1536 + hh * 64 + d;
    float sq = 0.f, sk = 0.f;
    for (int li = 0; li < 40; li++) {
        sq += b2f(base[(size_t)li * 1536]);
        sk += b2f(base[(size_t)li * 1536 + 512]);
    }
    QL[((size_t)hh * 256 + mm) * 64 + d] = sq * (1.f / 40.f);
    KL[((size_t)hh * 256 + mm) * 64 + d] = sk * (1.f / 40.f);
}

// fp32 in-place row softmax (a2)
__global__ __launch_bounds__(256) void row_softmax(
    float* __restrict__ S, float* __restrict__ LSUM, int ncols)
{
    int row = blockIdx.x;
    float* p = S + (size_t)row * ncols;
    int tid = threadIdx.x;
    __shared__ float sr1[4], sr2[4];
    float mx = -1e30f;
    for (int i = tid; i < ncols; i += 256) mx = fmaxf(mx, p[i]);
    for (int o = 1; o < 64; o <<= 1) mx = fmaxf(mx, __shfl_xor(mx, o, 64));
    if ((tid & 63) == 0) sr1[tid >> 6] = mx;
    __syncthreads();
    mx = fmaxf(fmaxf(sr1[0], sr1[1]), fmaxf(sr1[2], sr1[3]));
    float s = 0.f;
    for (int i = tid; i < ncols; i += 256) { float e = __expf(p[i] - mx); p[i] = e; s += e; }
    for (int o = 1; o < 64; o <<= 1) s += __shfl_xor(s, o, 64);
    if ((tid & 63) == 0) sr2[tid >> 6] = s;
    __syncthreads();
    s = sr2[0] + sr2[1] + sr2[2] + sr2[3];
    float inv = 1.f / s;
    if (tid == 0) LSUM[row] = inv;
    for (int i = tid; i < ncols; i += 256) p[i] *= inv;
}

// fp32 scores -> normalized bf16 probabilities
__global__ __launch_bounds__(256) void row_softmax_bf16(
    const float* __restrict__ S, u16* __restrict__ P, int ncols)
{
    int row = blockIdx.x;
    const float* p = S + (size_t)row * ncols;
    u16* q = P + (size_t)row * ncols;
    int tid = threadIdx.x;
    __shared__ float sr1[4], sr2[4];
    float mx = -1e30f;
    for (int i = tid; i < ncols; i += 256) mx = fmaxf(mx, p[i]);
    for (int o = 1; o < 64; o <<= 1) mx = fmaxf(mx, __shfl_xor(mx, o, 64));
    if ((tid & 63) == 0) sr1[tid >> 6] = mx;
    __syncthreads();
    mx = fmaxf(fmaxf(sr1[0], sr1[1]), fmaxf(sr1[2], sr1[3]));
    float s = 0.f;
    for (int i = tid; i < ncols; i += 256) s += __expf(p[i] - mx);
    for (int o = 1; o < 64; o <<= 1) s += __shfl_xor(s, o, 64);
    if ((tid & 63) == 0) sr2[tid >> 6] = s;
    __syncthreads();
    s = sr2[0] + sr2[1] + sr2[2] + sr2[3];
    float inv = 1.f / s;
    for (int i = tid; i < ncols; i += 256) q[i] = f2b(__expf(p[i] - mx) * inv);
}

__global__ __launch_bounds__(256) void a2norms_kernel(
    const float* __restrict__ A2, float* __restrict__ scal)
{
    int hh = blockIdx.x, tid = threadIdx.x;
    const float* A = A2 + (size_t)hh * 65536;
    float rs = 0.f, cs = 0.f;
    for (int j = 0; j < 256; j++) {
        rs += fabsf(A[(size_t)tid * 256 + j]);
        cs += fabsf(A[(size_t)j * 256 + tid]);
    }
    __shared__ float sm[8];
    for (int o = 1; o < 64; o <<= 1) {
        rs = fmaxf(rs, __shfl_xor(rs, o, 64));
        cs = fmaxf(cs, __shfl_xor(cs, o, 64));
    }
    if ((tid & 63) == 0) { sm[tid >> 6] = rs; sm[4 + (tid >> 6)] = cs; }
    __syncthreads();
    if (tid == 0) {
        float rm = fmaxf(fmaxf(sm[0], sm[1]), fmaxf(sm[2], sm[3]));
        float cm = fmaxf(fmaxf(sm[4], sm[5]), fmaxf(sm[6], sm[7]));
        atomicMax((unsigned int*)&scal[0], __float_as_uint(rm));
        atomicMax((unsigned int*)&scal[1], __float_as_uint(cm));
    }
}

__global__ __launch_bounds__(256) void z0_kernel(
    const float* __restrict__ A2, const float* __restrict__ scal, float* __restrict__ Z)
{
    int i = blockIdx.x, hh = blockIdx.y, j = threadIdx.x;
    float inv = 1.f / (scal[0] * scal[1]);
    Z[((size_t)hh * 256 + i) * 256 + j] = A2[((size_t)hh * 256 + j) * 256 + i] * inv;
}

// Tiny fused a1@Z for layer 1 (single token), q from bf16 QKVh
__global__ __launch_bounds__(256) void a1z_single(
    const u16* __restrict__ QKVh, const float* __restrict__ KL,
    const float* __restrict__ ZM, float* __restrict__ OUT, int tok)
{
    int h = blockIdx.x, tid = threadIdx.x;
    __shared__ float q[64];
    __shared__ float p[256];
    __shared__ float red[4];
    if (tid < 64) q[tid] = b2f(QKVh[(size_t)tok * 1536 + h * 64 + tid]);
    __syncthreads();
    const float* kl = KL + ((size_t)h * 256 + tid) * 64;
    float s = 0.f;
    for (int d = 0; d < 64; d++) s += q[d] * kl[d];
    float mx = s;
    for (int o = 1; o < 64; o <<= 1) mx = fmaxf(mx, __shfl_xor(mx, o, 64));
    if ((tid & 63) == 0) red[tid >> 6] = mx;
    __syncthreads();
    mx = fmaxf(fmaxf(red[0], red[1]), fmaxf(red[2], red[3]));
    float e = __expf(s - mx);
    float sum = e;
    for (int o = 1; o < 64; o <<= 1) sum += __shfl_xor(sum, o, 64);
    __syncthreads();
    if ((tid & 63) == 0) red[tid >> 6] = sum;
    __syncthreads();
    sum = red[0] + red[1] + red[2] + red[3];
    p[tid] = e / sum;
    __syncthreads();
    if (tid < 64) {
        float a = 0.f;
        for (int j = 0; j < 256; j++) a += p[j] * ZM[((size_t)h * 256 + j) * 64 + tid];
        OUT[(size_t)tok * 512 + h * 64 + tid] = a;
    }
}

// Depthwise 33-tap token conv of V (bf16), added into OUT (fp32)
__global__ __launch_bounds__(256) void conv_res(
    const u16* __restrict__ QKVh, float* __restrict__ OUT,
    const float* __restrict__ resw, int t0, int ntok)
{
    int idx = blockIdx.x * 256 + threadIdx.x;
    if (idx >= ntok * 512) return;
    int tok = t0 + (idx >> 9);
    int c = idx & 511;
    int h = c >> 6;
    const u16* vbase = QKVh + 1024 + c;
    float acc = 0.f;
    #pragma unroll 1
    for (int r = 0; r < 33; r++) {
        int ts = tok - 16 + r;
        if (ts >= 0 && ts < LPAD)
            acc += resw[h * 33 + r] * b2f(vbase[(size_t)ts * 1536]);
    }
    OUT[(size_t)tok * 512 + c] += acc;
}

// V slice of QKVh -> Vt[h][d][t] (bf16), LDS-tiled transpose
__global__ __launch_bounds__(256) void vtrans(
    const u16* __restrict__ QKVh, u16* __restrict__ Vt)
{
    int t0 = blockIdx.x * 64, hh = blockIdx.y;
    __shared__ u16 tile[64][65];
    #pragma unroll
    for (int ii = 0; ii < 16; ii++) {
        int idx = threadIdx.x + ii * 256;
        int t = idx >> 6, d = idx & 63;
        tile[t][d] = QKVh[(size_t)(t0 + t) * 1536 + 1024 + hh * 64 + d];
    }
    __syncthreads();
    #pragma unroll
    for (int ii = 0; ii < 16; ii++) {
        int idx = threadIdx.x + ii * 256;
        int d = idx >> 6, t = idx & 63;
        Vt[((size_t)hh * 64 + d) * LPAD + t0 + t] = tile[t][d];
    }
}

__global__ __launch_bounds__(256) void ppeg_kernel(
    const float* __restrict__ S, float* __restrict__ O,
    const float* __restrict__ w7t, const float* __restrict__ b7,
    const float* __restrict__ w5t, const float* __restrict__ b5,
    const float* __restrict__ w3t, const float* __restrict__ b3)
{
    int pos = blockIdx.x;
    int y = pos / 100, x = pos - y * 100;
    int c = blockIdx.y * 256 + threadIdx.x;
    float acc = S[(size_t)(1 + pos) * 512 + c] + b7[c] + b5[c] + b3[c];
    for (int dy = -3; dy <= 3; dy++) {
        int yy = y + dy; if ((unsigned)yy >= 100u) continue;
        for (int dx = -3; dx <= 3; dx++) {
            int xx = x + dx; if ((unsigned)xx >= 100u) continue;
            float v = S[(size_t)(1 + yy * 100 + xx) * 512 + c];
            float wsum = w7t[((dy + 3) * 7 + (dx + 3)) * 512 + c];
            if (dy >= -2 && dy <= 2 && dx >= -2 && dx <= 2)
                wsum += w5t[((dy + 2) * 5 + (dx + 2)) * 512 + c];
            if (dy >= -1 && dy <= 1 && dx >= -1 && dx <= 1)
                wsum += w3t[((dy + 1) * 3 + (dx + 1)) * 512 + c];
            acc += v * wsum;
        }
    }
    O[(size_t)(1 + pos) * 512 + c] = acc;
}

__global__ void transpose_w(const float* __restrict__ w, float* __restrict__ wt, int KK)
{
    int idx = blockIdx.x * 256 + threadIdx.x;
    if (idx >= 512 * KK) return;
    int c = idx / KK, k = idx - c * KK;
    wt[k * 512 + c] = w[idx];
}

__global__ __launch_bounds__(64) void final_kernel(
    const float* __restrict__ S, const float* __restrict__ g, const float* __restrict__ b,
    const float* __restrict__ w, const float* __restrict__ bb, float* __restrict__ out)
{
    int lane = threadIdx.x;
    float v[8]; float s = 0.f, s2 = 0.f;
    #pragma unroll
    for (int i = 0; i < 8; i++) { float t = S[lane + i * 64]; v[i] = t; s += t; s2 += t * t; }
    for (int o = 1; o < 64; o <<= 1) { s += __shfl_xor(s, o, 64); s2 += __shfl_xor(s2, o, 64); }
    float mu = s * (1.f / 512.f);
    float var = s2 * (1.f / 512.f) - mu * mu;
    float rs = rsqrtf(var + 1e-5f);
    float o0 = 0.f, o1 = 0.f;
    #pragma unroll
    for (int i = 0; i < 8; i++) {
        int j = lane + i * 64;
        float xn = (v[i] - mu) * rs * g[j] + b[j];
        o0 += xn * w[j * 2 + 0];
        o1 += xn * w[j * 2 + 1];
    }
    for (int o = 1; o < 64; o <<= 1) { o0 += __shfl_xor(o0, o, 64); o1 += __shfl_xor(o1, o, 64); }
    if (lane == 0) { out[0] = o0 + bb[0]; out[1] = o1 + bb[1]; }
}

__global__ void zerok(float* p, int n)
{
    int i = blockIdx.x * 256 + threadIdx.x;
    if (i < n) p[i] = 0.f;
}
__global__ void zero2k(float* p) { p[0] = 0.f; p[1] = 0.f; }
__global__ void copy512(float* dst, const float* src)
{
    int i = blockIdx.x * 256 + threadIdx.x;
    if (i < 512) dst[i] = src[i];
}
__global__ void cast_bf16(const float* __restrict__ src, u16* __restrict__ dst, int n)
{
    int i = (blockIdx.x * 256 + threadIdx.x) * 4;
    if (i >= n) return;
    float4 v = *(const float4*)(src + i);
    dst[i + 0] = f2b(v.x); dst[i + 1] = f2b(v.y);
    dst[i + 2] = f2b(v.z); dst[i + 3] = f2b(v.w);
}
// dst[b][c][r] = src[b][r][c]  (cast-transpose fp32 RxC -> bf16 CxR)
__global__ void castT(const float* __restrict__ src, u16* __restrict__ dst,
                      int R, int C, int nb)
{
    size_t idx = (size_t)blockIdx.x * 256 + threadIdx.x;
    size_t tot = (size_t)R * C * nb;
    if (idx >= tot) return;
    int rc = R * C;
    int b = (int)(idx / rc);
    int rem = (int)(idx - (size_t)b * rc);
    int c = rem / R, r = rem - c * R;
    dst[idx] = f2b(src[(size_t)b * rc + (size_t)r * C + c]);
}

// ---------------------------------------------------------------------------
extern "C" void kernel_launch(void* const* d_in, const int* in_sizes, int n_in,
                              void* d_out, int out_size, void* d_ws, size_t ws_size,
                              hipStream_t stream)
{
    const float* h     = (const float*)d_in[0];
    const float* fc1_w = (const float*)d_in[1];
    const float* fc1_b = (const float*)d_in[2];
    const float* cls   = (const float*)d_in[3];
    bool sigorder = (in_sizes[10] == 512 * 49);
    int i_l2 = sigorder ? 16 : 10;
    int i_pp = sigorder ? 10 : 16;
    const float* l_g[2]   = { (const float*)d_in[4], (const float*)d_in[i_l2 + 0] };
    const float* l_b[2]   = { (const float*)d_in[5], (const float*)d_in[i_l2 + 1] };
    const float* l_qkv[2] = { (const float*)d_in[6], (const float*)d_in[i_l2 + 2] };
    const float* l_ow[2]  = { (const float*)d_in[7], (const float*)d_in[i_l2 + 3] };
    const float* l_ob[2]  = { (const float*)d_in[8], (const float*)d_in[i_l2 + 4] };
    const float* l_rw[2]  = { (const float*)d_in[9], (const float*)d_in[i_l2 + 5] };
    const float* w7 = (const float*)d_in[i_pp + 0];
    const float* b7 = (const float*)d_in[i_pp + 1];
    const float* w5 = (const float*)d_in[i_pp + 2];
    const float* b5 = (const float*)d_in[i_pp + 3];
    const float* w3 = (const float*)d_in[i_pp + 4];
    const float* b3 = (const float*)d_in[i_pp + 5];
    const float* ng   = (const float*)d_in[22];
    const float* nbv  = (const float*)d_in[23];
    const float* fc2w = (const float*)d_in[24];
    const float* fc2b = (const float*)d_in[25];
    float* out = (float*)d_out;

    char* Wb = (char*)d_ws;
    size_t off = 0;
    auto allocB = [&](size_t bytes) { void* p = Wb + off; off = (off + bytes + 255) & ~(size_t)255; return p; };

    float* SEQ   = (float*)allocB((size_t)NSEQ * 512 * 4);
    float* XP    = (float*)allocB((size_t)LPAD * 512 * 4);
    u16*   XPh   = (u16*)  allocB((size_t)LPAD * 512 * 2);
    u16*   QKVh  = (u16*)  allocB((size_t)LPAD * 1536 * 2);
    float* QLKL  = (float*)allocB((size_t)262144 * 4);
    float* QL = QLKL, *KL = QLKL + 131072;
    u16*   QLKLh = (u16*)  allocB((size_t)262144 * 2);
    u16*   QLh = QLKLh, *KLh = QLKLh + 131072;
    float* A2   = (float*)allocB(524288 * 4);
    float* Zb   = (float*)allocB(524288 * 4);
    float* Z2b  = (float*)allocB(524288 * 4);
    float* XZ   = (float*)allocB(524288 * 4);
    float* W2b  = (float*)allocB(524288 * 4);
    float* W3b  = (float*)allocB(524288 * 4);
    float* A3V  = (float*)allocB(131072 * 4);
    float* ZMATf= (float*)allocB(131072 * 4);
    u16*   ZMATt= (u16*)  allocB(131072 * 2);
    u16*   Vt   = (u16*)  allocB((size_t)8 * 64 * LPAD * 2);
    u16*   fc1wt= (u16*)  allocB(524288 * 2);
    u16*   qkvwt= (u16*)  allocB(786432 * 2);
    u16*   outwt= (u16*)  allocB(262144 * 2);
    float* W7T  = (float*)allocB(25088 * 4);
    float* W5T  = (float*)allocB(12800 * 4);
    float* W3T  = (float*)allocB(4608 * 4);
    float* LSUM = (float*)allocB(2048 * 4);
    float* SCAL = (float*)allocB(16);
    // union1: hbf (fc1 input) / OUT (post-attn buffer, also SEQ2)
    void*  U1   = allocB((size_t)LPAD * 512 * 4);
    u16*   hbf  = (u16*)U1;
    float* OUT  = (float*)U1;
    float* SEQ2 = OUT;
    size_t fixed = off;

    size_t scB_b = (size_t)8 * 256 * LPAD * 4;   // batched SC (fp32 scores)
    size_t phB_b = (size_t)8 * 256 * LPAD * 2;   // batched Ph (bf16 probs)
    bool batched = ws_size >= fixed + scB_b + phB_b;
    float* SC; u16* Ph;
    if (batched) {
        SC = (float*)(Wb + fixed);
        Ph = (u16*)(Wb + fixed + scB_b);
    } else {
        SC = (float*)(Wb + fixed);
        Ph = (u16*)(Wb + fixed + (size_t)256 * LPAD * 4);
    }
    u16* OUTh = (u16*)SC;   // alias: SC dead by the time OUTh is materialized

    auto mgemm = [&](const u16* A, int lda, long sA, const u16* Bt, int ldb, long sB,
                     void* C, int ldc, long sC, int M, int N, int K,
                     const float* bias, const float* resid, int ldr,
                     int relu, int qscale, int obf16, int nbatch, int ksplit, int atomic) {
        dim3 grid((N + 127) / 128, (M + 127) / 128, nbatch * ksplit);
        gemm_mfma<<<grid, 256, 0, stream>>>(A, lda, sA, Bt, ldb, sB, C, ldc, sC,
            M, N, K, ksplit, bias, resid, ldr, relu, qscale, obf16, atomic);
    };
    auto fgemm = [&](const float* A, int lda, long sA, const float* B, int ldb, long sB,
                     float* C, int ldc, long sC, int M, int N, int K,
                     float alpha, float diagc, const float* bias,
                     const float* resid, int ldr, long sR, float rescoef,
                     int btrans, int nbatch) {
        dim3 grid(N / 64, (M + 63) / 64, nbatch);
        gemm_big<<<grid, 256, 0, stream>>>(A, lda, sA, B, ldb, sB, C, ldc, sC, M, N, K,
            alpha, diagc, bias, resid, ldr, sR, rescoef, btrans);
    };

    // ---- prologue: fc1 (bf16 MFMA) + cls + pads + weight transposes
    cast_bf16<<<(NPIX * 1024 / 4 + 255) / 256, 256, 0, stream>>>(h, hbf, NPIX * 1024);
    castT<<<(524288 + 255) / 256, 256, 0, stream>>>(fc1_w, fc1wt, 1024, 512, 1);
    mgemm(hbf, 1024, 0, fc1wt, 1024, 0, SEQ + 512, 512, 0, NPIX, 512, 1024,
          fc1_b, nullptr, 0, 1, 0, 0, 1, 1, 0);
    copy512<<<2, 256, 0, stream>>>(SEQ, cls);
    zerok<<<(PADT * 512 + 255) / 256, 256, 0, stream>>>(XP, PADT * 512);
    zerok<<<(PADT * 256 + 255) / 256, 256, 0, stream>>>((float*)XPh, PADT * 256);
    transpose_w<<<(512 * 49 + 255) / 256, 256, 0, stream>>>(w7, W7T, 49);
    transpose_w<<<(512 * 25 + 255) / 256, 256, 0, stream>>>(w5, W5T, 25);
    transpose_w<<<(512 * 9 + 255) / 256, 256, 0, stream>>>(w3, W3T, 9);

    for (int layer = 0; layer < 2; layer++) {
        const float* curSEQ = (layer == 0) ? SEQ : SEQ2;
        ln_kernel<<<(NSEQ + 3) / 4, 256, 0, stream>>>(curSEQ, XP + (size_t)PADT * 512,
            XPh + (size_t)PADT * 512, l_g[layer], l_b[layer], NSEQ);
        castT<<<(786432 + 255) / 256, 256, 0, stream>>>(l_qkv[layer], qkvwt, 512, 1536, 1);
        // qkv projection, q scaled 1/8, bf16 output
        mgemm(XPh, 512, 0, qkvwt, 512, 0, QKVh, 1536, 0, LPAD, 1536, 512,
              nullptr, nullptr, 0, 0, 1, 1, 1, 1, 0);
        landmarks_kernel<<<dim3(256, 8), 64, 0, stream>>>(QKVh, QL, KL);
        cast_bf16<<<(262144 / 4 + 255) / 256, 256, 0, stream>>>(QLKL, QLKLh, 262144);
        // a2 = softmax(ql @ kl^T)  (fp32)
        fgemm(QL, 64, 16384, KL, 64, 16384, A2, 256, 65536, 256, 256, 64,
              1.f, 0.f, nullptr, nullptr, 0, 0, 0.f, 1, 8);
        row_softmax<<<2048, 256, 0, stream>>>(A2, LSUM, 256);
        zero2k<<<1, 1, 0, stream>>>(SCAL);
        a2norms_kernel<<<8, 256, 0, stream>>>(A2, SCAL);
        z0_kernel<<<dim3(256, 8), 256, 0, stream>>>(A2, SCAL, Zb);
        // Newton-Schulz (fp32; ew7 folded: W2 = XZ@XZ - 7*XZ + 15I)
        float* zc = Zb; float* zn = Z2b;
        for (int it = 0; it < 6; it++) {
            fgemm(A2, 256, 65536, zc, 256, 65536, XZ, 256, 65536, 256, 256, 256,
                  1.f, 0.f, nullptr, nullptr, 0, 0, 0.f, 0, 8);
            fgemm(XZ, 256, 65536, XZ, 256, 65536, W2b, 256, 65536, 256, 256, 256,
                  1.f, 15.f, nullptr, XZ, 256, 65536, -7.f, 0, 8);
            fgemm(XZ, 256, 65536, W2b, 256, 65536, W3b, 256, 65536, 256, 256, 256,
                  -1.f, 13.f, nullptr, nullptr, 0, 0, 0.f, 0, 8);
            fgemm(zc, 256, 65536, W3b, 256, 65536, zn, 256, 65536, 256, 256, 256,
                  0.25f, 0.f, nullptr, nullptr, 0, 0, 0.f, 0, 8);
            float* t = zc; zc = zn; zn = t;
        }
        // a3v = softmax(ql @ k^T) @ v  via MFMA
        vtrans<<<dim3(160, 8), 256, 0, stream>>>(QKVh, Vt);
        zerok<<<512, 256, 0, stream>>>(A3V, 131072);
        if (batched) {
            mgemm(QLh, 64, 16384, QKVh + 512, 1536, 64, SC, LPAD, (long)256 * LPAD,
                  256, LPAD, 64, nullptr, nullptr, 0, 0, 0, 0, 8, 1, 0);
            row_softmax_bf16<<<2048, 256, 0, stream>>>(SC, Ph, LPAD);
            mgemm(Ph, LPAD, (long)256 * LPAD, Vt, LPAD, (long)64 * LPAD, A3V, 64, 16384,
                  256, 64, LPAD, nullptr, nullptr, 0, 0, 0, 0, 8, 40, 1);
        } else {
            for (int hh = 0; hh < 8; hh++) {
                mgemm(QLh + (size_t)hh * 16384, 64, 0, QKVh + 512 + hh * 64, 1536, 0,
                      SC, LPAD, 0, 256, LPAD, 64, nullptr, nullptr, 0, 0, 0, 0, 1, 1, 0);
                row_softmax_bf16<<<256, 256, 0, stream>>>(SC, Ph, LPAD);
                mgemm(Ph, LPAD, 0, Vt + (size_t)hh * 64 * LPAD, LPAD, 0,
                      A3V + (size_t)hh * 16384, 64, 0, 256, 64, LPAD,
                      nullptr, nullptr, 0, 0, 0, 0, 1, 40, 1);
            }
        }
        // ZMAT = pinv(a2) @ a3v  (fp32)
        fgemm(zc, 256, 65536, A3V, 64, 16384, ZMATf, 64, 16384, 256, 64, 256,
              1.f, 0.f, nullptr, nullptr, 0, 0, 0.f, 0, 8);

        if (layer == 0) {
            // a1 chain: scores -> softmax(bf16) -> @ZMAT, all MFMA
            castT<<<(131072 + 255) / 256, 256, 0, stream>>>(ZMATf, ZMATt, 256, 64, 8);
            if (batched) {
                mgemm(QKVh, 1536, 64, KLh, 64, 16384, SC, 256, (long)LPAD * 256,
                      LPAD, 256, 64, nullptr, nullptr, 0, 0, 0, 0, 8, 1, 0);
                row_softmax_bf16<<<8 * LPAD, 256, 0, stream>>>(SC, Ph, 256);
                mgemm(Ph, 256, (long)LPAD * 256, ZMATt, 256, 16384, OUT, 512, 64,
                      LPAD, 64, 256, nullptr, nullptr, 0, 0, 0, 0, 8, 1, 0);
            } else {
                for (int hh = 0; hh < 8; hh++) {
                    mgemm(QKVh + hh * 64, 1536, 0, KLh + (size_t)hh * 16384, 64, 0,
                          SC, 256, 0, LPAD, 256, 64, nullptr, nullptr, 0, 0, 0, 0, 1, 1, 0);
                    row_softmax_bf16<<<LPAD, 256, 0, stream>>>(SC, Ph, 256);
                    mgemm(Ph, 256, 0, ZMATt + (size_t)hh * 16384, 256, 0,
                          OUT + hh * 64, 512, 0, LPAD, 64, 256,
                          nullptr, nullptr, 0, 0, 0, 0, 1, 1, 0);
                }
            }
            conv_res<<<(NSEQ * 512 + 255) / 256, 256, 0, stream>>>(QKVh, OUT, l_rw[0], PADT, NSEQ);
            // out projection (MFMA) + bias + residual(LN'd x)
            cast_bf16<<<(NSEQ * 512 / 4 + 255) / 256, 256, 0, stream>>>(
                OUT + (size_t)PADT * 512, OUTh, NSEQ * 512);
            castT<<<(262144 + 255) / 256, 256, 0, stream>>>(l_ow[0], outwt, 512, 512, 1);
            mgemm(OUTh, 512, 0, outwt, 512, 0, SEQ, 512, 0, NSEQ, 512, 512,
                  l_ob[0], XP + (size_t)PADT * 512, 512, 0, 0, 0, 1, 1, 0);
            // PPEG: SEQ -> SEQ2 (=OUT, dead now)
            ppeg_kernel<<<dim3(10000, 2), 256, 0, stream>>>(SEQ, SEQ2, W7T, b7, W5T, b5, W3T, b3);
            copy512<<<2, 256, 0, stream>>>(SEQ2, SEQ);
        } else {
            // layer 1: only token PADT survives to the output
            a1z_single<<<8, 256, 0, stream>>>(QKVh, KL, ZMATf, OUT, PADT);
            conv_res<<<2, 256, 0, stream>>>(QKVh, OUT, l_rw[1], PADT, 1);
            fgemm(OUT + (size_t)PADT * 512, 512, 0, l_ow[1], 512, 0, SEQ, 512, 0,
                  1, 512, 512, 1.f, 0.f, l_ob[1],
                  XP + (size_t)PADT * 512, 512, 0, 1.f, 0, 1);
        }
    }
    final_kernel<<<1, 64, 0, stream>>>(SEQ, ng, nbv, fc2w, fc2b, out);
    (void)n_in; (void)out_size;
}